// Round 7
// baseline (81.569 us; speedup 1.0000x reference)
//
#include <hip/hip_runtime.h>

typedef float v2f __attribute__((ext_vector_type(2)));

#define BB 8192
#define NN 36
#define INF_ 8
#define HH 8
#define DHH 9
#define GATF 72
#define ACTF 10
#define NTH 576            // 9 waves; 2 graphs x 288 rows, zero masked lanes
#define ROWS 288           // HH*NN
#define HSTRIDE 12         // h row: 10 floats (9 + ssum-one), stride 12 (16B-aligned)
#define WSTRIDE 12
#define L2E 1.44269504088896f
#define MASKNEG -1000000.0f

static __device__ __forceinline__ v2f mk2(float a, float b) { v2f r; r.x = a; r.y = b; return r; }

__global__ __launch_bounds__(NTH, 6) void gnn_kernel(
    const float* __restrict__ x, const int* __restrict__ adj,
    const float* __restrict__ W, const float* __restrict__ a_src,
    const float* __restrict__ a_dst, const float* __restrict__ W_down,
    const float* __restrict__ b_down, const float* __restrict__ W_mu,
    const float* __restrict__ b_mu, float* __restrict__ out)
{
    const int tid = threadIdx.x;
    const int b0 = blockIdx.x * 2;

    // per-item buffers (x2)
    __shared__ float xcs[2 * NN * 9];                          // 2592 B
    __shared__ float ts[2 * NN];                               // 288 B
    __shared__ __align__(16) float hbuf[2 * HH * NN * HSTRIDE];// 27648 B
    __shared__ __align__(16) float edl[2 * ROWS];              // 2304 B
    __shared__ float pd[2 * NN * 9];                           // 2592 B
    __shared__ float feat[2 * GATF];                           // 576 B
    // shared across items
    __shared__ __align__(16) float adjf[NN * NN];              // 5184 B: 0 or MASKNEG
    __shared__ __align__(16) float wlds[HH * 7 * WSTRIDE];     // 2688 B
    __shared__ v2f  aid[HH * DHH];                             // 576 B {a_src,a_dst}
    __shared__ float wdlds[GATF];                              // 288 B
    __shared__ float wmulds[GATF * ACTF];                      // 2880 B
    __shared__ float bdlds[1];
    __shared__ float bmulds[ACTF];

    // ---- Phase 0: stage inputs ----
    {   // x for both items: 576 elements, exactly 1/thread (b0, b0+1 contiguous)
        const float* xb = x + (size_t)b0 * (NN * INF_);
        int item = (tid >= NN * INF_) ? 1 : 0;
        int rem = tid - item * (NN * INF_);
        int n = rem >> 3, c = rem & 7;
        float v = xb[tid];
        float* xc = xcs + item * (NN * 9);
        if (c < 3) xc[n * 9 + c] = v;
        else if (c > 3) xc[n * 9 + (c - 1)] = v;
        if (c == 4) ts[item * NN + n] = v;
    }
    if (tid < 324) {   // adj -> additive float mask, 4 elements per thread
        int i = tid / 9, q = tid - i * 9;
        int4 a4 = reinterpret_cast<const int4*>(adj)[tid];
        float4 m4;
        m4.x = (a4.x > 0) ? 0.f : MASKNEG;
        m4.y = (a4.y > 0) ? 0.f : MASKNEG;
        m4.z = (a4.z > 0) ? 0.f : MASKNEG;
        m4.w = (a4.w > 0) ? 0.f : MASKNEG;
        *reinterpret_cast<float4*>(adjf + i * NN + q * 4) = m4;
    }
    if (tid >= 384 && tid < 384 + HH * 7 * DHH - 504 + 504) { /* no-op guard */ }
    for (int idx = tid; idx < HH * 7 * DHH; idx += NTH) {
        int row = idx / DHH, d = idx - row * DHH;
        wlds[row * WSTRIDE + d] = W[idx];
    }
    if (tid < HH * DHH) aid[tid] = mk2(a_src[tid], a_dst[tid]);
    if (tid >= 448 && tid < 448 + GATF) wdlds[tid - 448] = W_down[tid - 448];
    for (int idx = tid; idx < GATF * ACTF; idx += NTH) wmulds[idx] = W_mu[idx];
    if (tid == 0) bdlds[0] = b_down[0];
    if (tid >= 352 && tid < 352 + ACTF) bmulds[tid - 352] = b_mu[tid - 352];
    __syncthreads();

    // ---- Phase 1+2: all 576 threads: one (item,h,i) row each ----
    const int item = (tid >= ROWS) ? 1 : 0;
    const int r = tid - item * ROWS;            // 0..287
    const int hh = r / NN, i = r - hh * NN;
    float esr;
    {
        const float* xp = xcs + item * (NN * 9) + i * 9;
        const float* wp = wlds + hh * 7 * WSTRIDE;
        v2f h01 = mk2(0.f, 0.f), h23 = h01, h45 = h01, h67 = h01;
        float h8 = 0.f;
        #pragma unroll
        for (int k = 0; k < 7; ++k) {
            float xk = xp[k];
            v2f xkk = mk2(xk, xk);
            const float* wr = wp + k * WSTRIDE;
            float4 wa = *reinterpret_cast<const float4*>(wr);
            float4 wb = *reinterpret_cast<const float4*>(wr + 4);
            float  wc = wr[8];
            h01 = __builtin_elementwise_fma(xkk, mk2(wa.x, wa.y), h01);
            h23 = __builtin_elementwise_fma(xkk, mk2(wa.z, wa.w), h23);
            h45 = __builtin_elementwise_fma(xkk, mk2(wb.x, wb.y), h45);
            h67 = __builtin_elementwise_fma(xkk, mk2(wb.z, wb.w), h67);
            h8 = fmaf(xk, wc, h8);
        }
        float* hp = hbuf + (item * ROWS + hh * NN + i) * HSTRIDE;
        *reinterpret_cast<float4*>(hp)     = make_float4(h01.x, h01.y, h23.x, h23.y);
        *reinterpret_cast<float4*>(hp + 4) = make_float4(h45.x, h45.y, h67.x, h67.y);
        *reinterpret_cast<v2f*>(hp + 8)    = mk2(h8, 1.0f);   // h[9]=1 -> ssum via PV
        const v2f* ap = aid + hh * DHH;
        v2f sd = mk2(0.f, 0.f);
        sd = __builtin_elementwise_fma(mk2(h01.x, h01.x), ap[0], sd);
        sd = __builtin_elementwise_fma(mk2(h01.y, h01.y), ap[1], sd);
        sd = __builtin_elementwise_fma(mk2(h23.x, h23.x), ap[2], sd);
        sd = __builtin_elementwise_fma(mk2(h23.y, h23.y), ap[3], sd);
        sd = __builtin_elementwise_fma(mk2(h45.x, h45.x), ap[4], sd);
        sd = __builtin_elementwise_fma(mk2(h45.y, h45.y), ap[5], sd);
        sd = __builtin_elementwise_fma(mk2(h67.x, h67.x), ap[6], sd);
        sd = __builtin_elementwise_fma(mk2(h67.y, h67.y), ap[7], sd);
        sd = __builtin_elementwise_fma(mk2(h8, h8), ap[8], sd);
        esr = sd.x * L2E;
        edl[item * ROWS + hh * NN + i] = sd.y * L2E;
    }
    __syncthreads();

    // ---- Phase 3: attention row + PV(+ssum) + ELU + fused down partial ----
    {
        const float* hrow = hbuf + (item * ROWS + hh * NN) * HSTRIDE;
        const float* edp = edl + item * ROWS + hh * NN;
        const float* amr = adjf + i * NN;
        v2f acc01 = mk2(0.f, 0.f), acc23 = acc01, acc45 = acc01, acc67 = acc01, acc89 = acc01;

#define STEP(jj, ee, mm) { \
        float s_ = esr + (ee); \
        float e_ = fmaxf(s_, 0.2f * s_) + (mm);          /* leaky + additive mask */ \
        float p_ = __builtin_exp2f(e_);                  /* masked -> exact 0 */ \
        const float* hj_ = hrow + (jj) * HSTRIDE; \
        float4 ha_ = *reinterpret_cast<const float4*>(hj_); \
        float4 hb_ = *reinterpret_cast<const float4*>(hj_ + 4); \
        v2f hc_ = *reinterpret_cast<const v2f*>(hj_ + 8); \
        v2f pp_ = mk2(p_, p_); \
        acc01 = __builtin_elementwise_fma(pp_, mk2(ha_.x, ha_.y), acc01); \
        acc23 = __builtin_elementwise_fma(pp_, mk2(ha_.z, ha_.w), acc23); \
        acc45 = __builtin_elementwise_fma(pp_, mk2(hb_.x, hb_.y), acc45); \
        acc67 = __builtin_elementwise_fma(pp_, mk2(hb_.z, hb_.w), acc67); \
        acc89 = __builtin_elementwise_fma(pp_, hc_, acc89); }

        #pragma unroll
        for (int q = 0; q < 9; ++q) {
            float4 e4 = *reinterpret_cast<const float4*>(edp + q * 4);
            float4 m4 = *reinterpret_cast<const float4*>(amr + q * 4);
            STEP(4 * q + 0, e4.x, m4.x);
            STEP(4 * q + 1, e4.y, m4.y);
            STEP(4 * q + 2, e4.z, m4.z);
            STEP(4 * q + 3, e4.w, m4.w);
        }
#undef STEP

        float inv = 1.0f / acc89.y;                       // ssum from h[9]=1 column
        v2f inv2 = mk2(inv, inv);
        v2f o01 = acc01 * inv2, o23 = acc23 * inv2, o45 = acc45 * inv2, o67 = acc67 * inv2;
        float o8 = acc89.x * inv;
        const float* wdp = wdlds + hh * DHH;
        float pdown = 0.f;
#define EPI(oval, dd_) { \
        float o_ = (oval); \
        o_ = (o_ > 0.f) ? o_ : (__builtin_exp2f(o_ * L2E) - 1.0f); \
        pdown = fmaf(o_, wdp[dd_], pdown); }
        EPI(o01.x, 0); EPI(o01.y, 1); EPI(o23.x, 2); EPI(o23.y, 3);
        EPI(o45.x, 4); EPI(o45.y, 5); EPI(o67.x, 6); EPI(o67.y, 7);
        EPI(o8, 8);
#undef EPI
        pd[item * (NN * 9) + i * 9 + hh] = pdown;
    }
    __syncthreads();

    // ---- Phase 4: down + feat = leaky_relu(concat(down, t), 0.01) ----
    if (tid < 2 * NN) {
        int it = (tid >= NN) ? 1 : 0;
        int node = tid - it * NN;
        const float* pp = pd + it * (NN * 9) + node * 9;
        float acc = bdlds[0];
        #pragma unroll
        for (int h = 0; h < HH; ++h) acc += pp[h];
        feat[it * GATF + node] = (acc > 0.f) ? acc : 0.01f * acc;
    } else if (tid < 4 * NN) {
        int idx = tid - 2 * NN;
        int it = (idx >= NN) ? 1 : 0;
        int node = idx - it * NN;
        float v = ts[it * NN + node];
        feat[it * GATF + NN + node] = (v > 0.f) ? v : 0.01f * v;
    }
    __syncthreads();

    // ---- Phase 5: mu = feat @ W_mu + b_mu (2 items x 10 outputs) ----
    if (tid < 2 * ACTF) {
        int it = (tid >= ACTF) ? 1 : 0;
        int o = tid - it * ACTF;
        const float* fp = feat + it * GATF;
        float acc = bmulds[o];
        #pragma unroll
        for (int k = 0; k < GATF; ++k) acc = fmaf(fp[k], wmulds[k * ACTF + o], acc);
        out[(size_t)(b0 + it) * ACTF + o] = acc;
    }
}

extern "C" void kernel_launch(void* const* d_in, const int* in_sizes, int n_in,
                              void* d_out, int out_size, void* d_ws, size_t ws_size,
                              hipStream_t stream) {
    const float* x      = (const float*)d_in[0];
    const int*   adj    = (const int*)d_in[1];
    const float* W      = (const float*)d_in[2];
    const float* a_src  = (const float*)d_in[3];
    const float* a_dst  = (const float*)d_in[4];
    const float* W_down = (const float*)d_in[5];
    const float* b_down = (const float*)d_in[6];
    const float* W_mu   = (const float*)d_in[7];
    const float* b_mu   = (const float*)d_in[8];
    float* out = (float*)d_out;

    gnn_kernel<<<BB / 2, NTH, 0, stream>>>(x, adj, W, a_src, a_dst, W_down, b_down, W_mu, b_mu, out);
}

// Round 8
// 79.403 us; speedup vs baseline: 1.0273x; 1.0273x over previous
//
#include <hip/hip_runtime.h>

typedef float v2f __attribute__((ext_vector_type(2)));

#define BB 8192
#define NN 36
#define INF_ 8
#define HH 8
#define DHH 9
#define GATF 72
#define ACTF 10
#define NTH 320
#define ROWS 288
#define HSTRIDE 12         // h row: 10 floats (9 + ones), stride 12 (16B-aligned)
#define WSTRIDE 12
#define L2E 1.44269504088896f
#define MASKNEG -1000000.0f

static __device__ __forceinline__ v2f mk2(float a, float b) { v2f r; r.x = a; r.y = b; return r; }

// Forced packed fp32 FMA (VOP3P). hipcc scalarizes ext_vector fp32 math
// (round 5/6 A/B: v2f builtins == scalar, identical time & VGPR), so emit
// v_pk_fma_f32 explicitly.
static __device__ __forceinline__ v2f pkfma(v2f a, v2f b, v2f c) {
    v2f d;
    asm("v_pk_fma_f32 %0, %1, %2, %3" : "=v"(d) : "v"(a), "v"(b), "v"(c));
    return d;
}

__global__ __launch_bounds__(NTH, 6) void gnn_kernel(
    const float* __restrict__ x, const int* __restrict__ adj,
    const float* __restrict__ W, const float* __restrict__ a_src,
    const float* __restrict__ a_dst, const float* __restrict__ W_down,
    const float* __restrict__ b_down, const float* __restrict__ W_mu,
    const float* __restrict__ b_mu, float* __restrict__ out)
{
    const int b = blockIdx.x;
    const int tid = threadIdx.x;

    __shared__ float xcs[NN * 9];                          // 1296 B
    __shared__ float ts[NN];                               // 144 B
    __shared__ __align__(16) float hbuf[ROWS * HSTRIDE];   // 13824 B
    __shared__ __align__(16) float edl[ROWS];              // 1152 B
    __shared__ __align__(16) float adjf[NN * NN];          // 5184 B: 0 or MASKNEG
    __shared__ float pd[NN * 9];                           // 1296 B
    __shared__ float feat[GATF];                           // 288 B
    __shared__ __align__(16) float wlds[HH * 7 * WSTRIDE]; // 2688 B
    __shared__ v2f  aid[HH * DHH];                         // 576 B {a_src,a_dst}
    __shared__ float wdlds[GATF];                          // 288 B
    __shared__ float wmulds[GATF * ACTF];                  // 2880 B
    __shared__ float bdlds[1];
    __shared__ float bmulds[ACTF];

    // ---- Phase 0: stage inputs ----
    const float* xb = x + (size_t)b * (NN * INF_);
    if (tid < NN * INF_) {
        int n = tid >> 3, c = tid & 7;
        float v = xb[tid];
        if (c < 3) xcs[n * 9 + c] = v;
        else if (c > 3) xcs[n * 9 + (c - 1)] = v;
        if (c == 4) ts[n] = v;
    }
    // adj -> additive float mask; 324 int4 quads, grid-stride over 320 threads
    for (int idx = tid; idx < (NN * NN) / 4; idx += NTH) {
        int4 a4 = reinterpret_cast<const int4*>(adj)[idx];
        float4 m4;
        m4.x = (a4.x > 0) ? 0.f : MASKNEG;
        m4.y = (a4.y > 0) ? 0.f : MASKNEG;
        m4.z = (a4.z > 0) ? 0.f : MASKNEG;
        m4.w = (a4.w > 0) ? 0.f : MASKNEG;
        *reinterpret_cast<float4*>(adjf + idx * 4) = m4;
    }
    for (int idx = tid; idx < HH * 7 * DHH; idx += NTH) {
        int row = idx / DHH, d = idx - row * DHH;
        wlds[row * WSTRIDE + d] = W[idx];
    }
    if (tid < HH * DHH) aid[tid] = mk2(a_src[tid], a_dst[tid]);
    if (tid >= 128 && tid < 128 + GATF) wdlds[tid - 128] = W_down[tid - 128];
    for (int idx = tid; idx < GATF * ACTF; idx += NTH) wmulds[idx] = W_mu[idx];
    if (tid == 0) bdlds[0] = b_down[0];
    if (tid >= 64 && tid < 64 + ACTF) bmulds[tid - 64] = b_mu[tid - 64];
    __syncthreads();

    // ---- Phase 1+2: per (h,i) row: h-row (pk_fma), es (reg), ed (LDS) ----
    const int hh = (tid < ROWS) ? (tid / NN) : 0;
    const int i  = (tid < ROWS) ? (tid - hh * NN) : 0;
    float esr = 0.f;
    if (tid < ROWS) {
        const float* xp = xcs + i * 9;
        const float* wp = wlds + hh * 7 * WSTRIDE;
        v2f h01 = mk2(0.f, 0.f), h23 = h01, h45 = h01, h67 = h01;
        float h8 = 0.f;
        #pragma unroll
        for (int k = 0; k < 7; ++k) {
            float xk = xp[k];
            v2f xkk = mk2(xk, xk);
            const float* wr = wp + k * WSTRIDE;
            float4 wa = *reinterpret_cast<const float4*>(wr);
            float4 wb = *reinterpret_cast<const float4*>(wr + 4);
            float  wc = wr[8];
            h01 = pkfma(xkk, *(const v2f*)&wa.x, h01);
            h23 = pkfma(xkk, *(const v2f*)&wa.z, h23);
            h45 = pkfma(xkk, *(const v2f*)&wb.x, h45);
            h67 = pkfma(xkk, *(const v2f*)&wb.z, h67);
            h8 = fmaf(xk, wc, h8);
        }
        float* hp = hbuf + (hh * NN + i) * HSTRIDE;
        *reinterpret_cast<float4*>(hp)     = make_float4(h01.x, h01.y, h23.x, h23.y);
        *reinterpret_cast<float4*>(hp + 4) = make_float4(h45.x, h45.y, h67.x, h67.y);
        *reinterpret_cast<v2f*>(hp + 8)    = mk2(h8, 1.0f);   // ones column -> ssum via PV
        const v2f* ap = aid + hh * DHH;
        v2f sd = mk2(0.f, 0.f);
        sd = pkfma(mk2(h01.x, h01.x), ap[0], sd);
        sd = pkfma(mk2(h01.y, h01.y), ap[1], sd);
        sd = pkfma(mk2(h23.x, h23.x), ap[2], sd);
        sd = pkfma(mk2(h23.y, h23.y), ap[3], sd);
        sd = pkfma(mk2(h45.x, h45.x), ap[4], sd);
        sd = pkfma(mk2(h45.y, h45.y), ap[5], sd);
        sd = pkfma(mk2(h67.x, h67.x), ap[6], sd);
        sd = pkfma(mk2(h67.y, h67.y), ap[7], sd);
        sd = pkfma(mk2(h8, h8), ap[8], sd);
        esr = sd.x * L2E;
        edl[hh * NN + i] = sd.y * L2E;
    }
    __syncthreads();

    // ---- Phase 3: attention row + PV(+ssum) + ELU + fused down partial ----
    if (tid < ROWS) {
        const float* hrow = hbuf + (hh * NN) * HSTRIDE;
        const float* edp = edl + hh * NN;
        const float* amr = adjf + i * NN;
        v2f acc01 = mk2(0.f, 0.f), acc23 = acc01, acc45 = acc01, acc67 = acc01, acc89 = acc01;

#define STEP(jj, ee, mm) { \
        float s_ = esr + (ee); \
        float e_ = fmaxf(s_, 0.2f * s_) + (mm);          /* leaky + additive mask */ \
        float p_ = __builtin_exp2f(e_);                  /* masked -> exact 0 */ \
        const float* hj_ = hrow + (jj) * HSTRIDE; \
        float4 ha_ = *reinterpret_cast<const float4*>(hj_); \
        float4 hb_ = *reinterpret_cast<const float4*>(hj_ + 4); \
        v2f hc_ = *reinterpret_cast<const v2f*>(hj_ + 8); \
        v2f pp_ = mk2(p_, p_); \
        acc01 = pkfma(pp_, *(const v2f*)&ha_.x, acc01); \
        acc23 = pkfma(pp_, *(const v2f*)&ha_.z, acc23); \
        acc45 = pkfma(pp_, *(const v2f*)&hb_.x, acc45); \
        acc67 = pkfma(pp_, *(const v2f*)&hb_.z, acc67); \
        acc89 = pkfma(pp_, hc_, acc89); }

        #pragma unroll
        for (int q = 0; q < 9; ++q) {
            float4 e4 = *reinterpret_cast<const float4*>(edp + q * 4);
            float4 m4 = *reinterpret_cast<const float4*>(amr + q * 4);
            STEP(4 * q + 0, e4.x, m4.x);
            STEP(4 * q + 1, e4.y, m4.y);
            STEP(4 * q + 2, e4.z, m4.z);
            STEP(4 * q + 3, e4.w, m4.w);
        }
#undef STEP

        float inv = 1.0f / acc89.y;                       // ssum from ones column
        v2f inv2 = mk2(inv, inv);
        v2f o01 = acc01 * inv2, o23 = acc23 * inv2, o45 = acc45 * inv2, o67 = acc67 * inv2;
        float o8 = acc89.x * inv;
        const float* wdp = wdlds + hh * DHH;
        float pdown = 0.f;
#define EPI(oval, dd_) { \
        float o_ = (oval); \
        o_ = (o_ > 0.f) ? o_ : (__builtin_exp2f(o_ * L2E) - 1.0f); \
        pdown = fmaf(o_, wdp[dd_], pdown); }
        EPI(o01.x, 0); EPI(o01.y, 1); EPI(o23.x, 2); EPI(o23.y, 3);
        EPI(o45.x, 4); EPI(o45.y, 5); EPI(o67.x, 6); EPI(o67.y, 7);
        EPI(o8, 8);
#undef EPI
        pd[i * 9 + hh] = pdown;
    }
    __syncthreads();

    // ---- Phase 4: down + feat = leaky_relu(concat(down, t), 0.01) ----
    if (tid < NN) {
        const float* pp = pd + tid * 9;
        float acc = bdlds[0];
        #pragma unroll
        for (int h = 0; h < HH; ++h) acc += pp[h];
        feat[tid] = (acc > 0.f) ? acc : 0.01f * acc;
    } else if (tid < 2 * NN) {
        float v = ts[tid - NN];
        feat[tid] = (v > 0.f) ? v : 0.01f * v;
    }
    __syncthreads();

    // ---- Phase 5: mu = feat @ W_mu + b_mu ----
    if (tid < ACTF) {
        float acc = bmulds[tid];
        #pragma unroll
        for (int k = 0; k < GATF; ++k) acc = fmaf(feat[k], wmulds[k * ACTF + tid], acc);
        out[(size_t)b * ACTF + tid] = acc;
    }
}

extern "C" void kernel_launch(void* const* d_in, const int* in_sizes, int n_in,
                              void* d_out, int out_size, void* d_ws, size_t ws_size,
                              hipStream_t stream) {
    const float* x      = (const float*)d_in[0];
    const int*   adj    = (const int*)d_in[1];
    const float* W      = (const float*)d_in[2];
    const float* a_src  = (const float*)d_in[3];
    const float* a_dst  = (const float*)d_in[4];
    const float* W_down = (const float*)d_in[5];
    const float* b_down = (const float*)d_in[6];
    const float* W_mu   = (const float*)d_in[7];
    const float* b_mu   = (const float*)d_in[8];
    float* out = (float*)d_out;

    gnn_kernel<<<BB, NTH, 0, stream>>>(x, adj, W, a_src, a_dst, W_down, b_down, W_mu, b_mu, out);
}